// Round 1
// baseline (2926.956 us; speedup 1.0000x reference)
//
#include <hip/hip_runtime.h>
#include <cstdint>
#include <cstddef>

#define HD 128
#define EDGED 16
#define NODED 64
#define LN_EPS 1e-5f

__device__ __forceinline__ float gelu_exact(float x) {
    return 0.5f * x * (1.0f + erff(x * 0.7071067811865475f));
}

// out[c*R + r] = in[r*C + c]   (in is [R,C] row-major)
__global__ void transpose_k(const float* __restrict__ in, float* __restrict__ out, int R, int C) {
    int idx = blockIdx.x * blockDim.x + threadIdx.x;
    if (idx < R * C) {
        int r = idx / C, c = idx - r * C;
        out[c * R + r] = in[idx];
    }
}

// C[M,NC] = act(A[M,K] @ Bt[K,NC] + bias), optional fused column sum/sumsq stats.
// Block: 256 threads, tile 64 rows x NC cols. Thread (ng=t/32, cg=t%32) owns
// rows ng*8..ng*8+7, cols {cg + 32*m}. Strided col mapping -> conflict-free
// b32 LDS reads of B (bank = cg).
template<int K, int NC, int ACT, int STATS>
__launch_bounds__(256)
__global__ void gemm_k(const float* __restrict__ A, const float* __restrict__ Bt,
                       const float* __restrict__ bias, float* __restrict__ C,
                       int M, float* __restrict__ stats)
{
    constexpr int CPT = NC / 32;
    constexpr int NB4 = 32 * NC / 1024;   // float4 loads of B per thread per chunk
    __shared__ float A_lds[64][36];
    __shared__ float B_lds[32][NC];
    __shared__ float st_lds[2][HD];

    const int t  = threadIdx.x;
    const int cg = t & 31;
    const int ng = t >> 5;
    const int row0 = blockIdx.x * 64;

    float acc[8][CPT];
#pragma unroll
    for (int i = 0; i < 8; ++i)
#pragma unroll
        for (int m = 0; m < CPT; ++m) acc[i][m] = 0.f;

    const int ar  = t >> 2;
    const int akp = (t & 3) * 8;
    const bool arow_ok = (row0 + ar) < M;
    const float* aptr = A + (size_t)(row0 + ar) * K + akp;

    for (int kc = 0; kc < K; kc += 32) {
        float4 a0 = make_float4(0.f, 0.f, 0.f, 0.f), a1 = a0;
        if (arow_ok) {
            const float4* p = (const float4*)(aptr + kc);
            a0 = p[0]; a1 = p[1];
        }
        float4 breg[NB4];
        const float4* Bsrc = (const float4*)(Bt + (size_t)kc * NC);
#pragma unroll
        for (int m = 0; m < NB4; ++m) breg[m] = Bsrc[m * 256 + t];

        __syncthreads();
        *(float4*)&A_lds[ar][akp]     = a0;
        *(float4*)&A_lds[ar][akp + 4] = a1;
#pragma unroll
        for (int m = 0; m < NB4; ++m) {
            int idx = m * 256 + t;
            *(float4*)&((float*)B_lds)[idx * 4] = breg[m];
        }
        __syncthreads();

#pragma unroll 4
        for (int kk = 0; kk < 32; ++kk) {
            float b[CPT];
#pragma unroll
            for (int m = 0; m < CPT; ++m) b[m] = B_lds[kk][cg + 32 * m];
#pragma unroll
            for (int i = 0; i < 8; ++i) {
                float a = A_lds[ng * 8 + i][kk];
#pragma unroll
                for (int m = 0; m < CPT; ++m) acc[i][m] = fmaf(a, b[m], acc[i][m]);
            }
        }
    }

    float bv[CPT];
#pragma unroll
    for (int m = 0; m < CPT; ++m) bv[m] = bias[cg + 32 * m];

    if (STATS) {
        if (t < HD) { st_lds[0][t] = 0.f; st_lds[1][t] = 0.f; }
        __syncthreads();
    }

    float s1[CPT], s2[CPT];
#pragma unroll
    for (int m = 0; m < CPT; ++m) { s1[m] = 0.f; s2[m] = 0.f; }

#pragma unroll
    for (int i = 0; i < 8; ++i) {
        int row = row0 + ng * 8 + i;
        if (row < M) {
#pragma unroll
            for (int m = 0; m < CPT; ++m) {
                float v = acc[i][m] + bv[m];
                if (ACT == 1) v = gelu_exact(v);
                C[(size_t)row * NC + cg + 32 * m] = v;
                if (STATS) { s1[m] += v; s2[m] += v * v; }
            }
        }
    }

    if (STATS) {
#pragma unroll
        for (int m = 0; m < CPT; ++m) {
            atomicAdd(&st_lds[0][cg + 32 * m], s1[m]);
            atomicAdd(&st_lds[1][cg + 32 * m], s2[m]);
        }
        __syncthreads();
        if (t < HD) {
            atomicAdd(&stats[t],      st_lds[0][t]);
            atomicAdd(&stats[HD + t], st_lds[1][t]);
        }
    }
}

// LayerNorm(+ReLU) over rows of 128, one wave per node, 2 cols/lane
__global__ void ln_relu_k(const float* __restrict__ y, const float* __restrict__ gam,
                          const float* __restrict__ bet, float* __restrict__ h, int N)
{
    int lane = threadIdx.x & 63;
    int c0 = lane * 2;
    float2 g2 = *(const float2*)&gam[c0];
    float2 b2 = *(const float2*)&bet[c0];
    int wid = (blockIdx.x * blockDim.x + threadIdx.x) >> 6;
    int nw  = (gridDim.x * blockDim.x) >> 6;
    for (int n = wid; n < N; n += nw) {
        float2 v = *(const float2*)&y[(size_t)n * HD + c0];
        float s = v.x + v.y;
        float q = v.x * v.x + v.y * v.y;
#pragma unroll
        for (int o = 32; o > 0; o >>= 1) { s += __shfl_xor(s, o, 64); q += __shfl_xor(q, o, 64); }
        float mu  = s * (1.f / 128.f);
        float inv = rsqrtf(q * (1.f / 128.f) - mu * mu + LN_EPS);
        float2 r;
        r.x = fmaxf(fmaf((v.x - mu) * inv, g2.x, b2.x), 0.f);
        r.y = fmaxf(fmaf((v.y - mu) * inv, g2.y, b2.y), 0.f);
        *(float2*)&h[(size_t)n * HD + c0] = r;
    }
}

// one wave: embed the single learned self-loop attr -> sl_vec[128]
__global__ void sl_embed_k(const float* __restrict__ attr, const float* __restrict__ W,
                           const float* __restrict__ bias, const float* __restrict__ gam,
                           const float* __restrict__ bet, float* __restrict__ out)
{
    int lane = threadIdx.x;
    int c0 = lane * 2, c1 = c0 + 1;
    float acc0 = bias[c0], acc1 = bias[c1];
    for (int k = 0; k < EDGED; ++k) {
        float a = attr[k];
        acc0 = fmaf(a, W[c0 * EDGED + k], acc0);
        acc1 = fmaf(a, W[c1 * EDGED + k], acc1);
    }
    float s = acc0 + acc1, q = acc0 * acc0 + acc1 * acc1;
#pragma unroll
    for (int o = 32; o > 0; o >>= 1) { s += __shfl_xor(s, o, 64); q += __shfl_xor(q, o, 64); }
    float mu  = s * (1.f / 128.f);
    float inv = rsqrtf(q * (1.f / 128.f) - mu * mu + LN_EPS);
    out[c0] = fmaxf(fmaf((acc0 - mu) * inv, gam[c0], bet[c0]), 0.f);
    out[c1] = fmaxf(fmaf((acc1 - mu) * inv, gam[c1], bet[c1]), 0.f);
}

// aggr[n][c] = h[n][c] + sl_vec[c]  (self-loop init, float4)
__global__ void add_sl_k(const float* __restrict__ h, const float* __restrict__ slv,
                         float* __restrict__ aggr, int total4)
{
    int idx = blockIdx.x * blockDim.x + threadIdx.x;
    if (idx < total4) {
        float4 a  = ((const float4*)h)[idx];
        float4 sv = ((const float4*)slv)[idx & 31];
        a.x += sv.x; a.y += sv.y; a.z += sv.z; a.w += sv.w;
        ((float4*)aggr)[idx] = a;
    }
}

// wave per edge: ea = ReLU(LN(attr @ W^T + b)); aggr[dst] += h[src] + ea
__launch_bounds__(256)
__global__ void edge_k(const float* __restrict__ h, const int* __restrict__ ei,
                       const float* __restrict__ eattr, const float* __restrict__ W,
                       const float* __restrict__ bias, const float* __restrict__ gam,
                       const float* __restrict__ bet, float* __restrict__ aggr, int E)
{
    __shared__ float Wt[EDGED * HD];   // [k][c] transposed for conflict-light b64 reads
    const int t = threadIdx.x;
#pragma unroll
    for (int m = 0; m < EDGED * HD / 256; ++m) {
        int idx = m * 256 + t;
        int c = idx >> 4, k = idx & 15;
        Wt[k * HD + c] = W[idx];
    }
    const int lane = t & 63;
    const int c0 = lane * 2;
    const float2 b2 = *(const float2*)&bias[c0];
    const float2 g2 = *(const float2*)&gam[c0];
    const float2 e2 = *(const float2*)&bet[c0];
    __syncthreads();

    int wid = (blockIdx.x * 256 + t) >> 6;
    int nw  = (gridDim.x * 256) >> 6;
    for (int e = wid; e < E; e += nw) {
        int src = ei[e];
        int dst = ei[E + e];
        float av = (lane < EDGED) ? eattr[(size_t)e * EDGED + lane] : 0.f;
        float acc0 = b2.x, acc1 = b2.y;
#pragma unroll
        for (int k = 0; k < EDGED; ++k) {
            float ak = __shfl(av, k, 64);
            float2 w = *(const float2*)&Wt[k * HD + c0];
            acc0 = fmaf(ak, w.x, acc0);
            acc1 = fmaf(ak, w.y, acc1);
        }
        float s = acc0 + acc1;
        float q = fmaf(acc0, acc0, acc1 * acc1);
#pragma unroll
        for (int o = 32; o > 0; o >>= 1) { s += __shfl_xor(s, o, 64); q += __shfl_xor(q, o, 64); }
        float mu  = s * (1.f / 128.f);
        float inv = rsqrtf(q * (1.f / 128.f) - mu * mu + LN_EPS);
        float v0 = fmaxf(fmaf((acc0 - mu) * inv, g2.x, e2.x), 0.f);
        float v1 = fmaxf(fmaf((acc1 - mu) * inv, g2.y, e2.y), 0.f);
        float2 hv = *(const float2*)&h[(size_t)src * HD + c0];
        unsafeAtomicAdd(&aggr[(size_t)dst * HD + c0],     v0 + hv.x);
        unsafeAtomicAdd(&aggr[(size_t)dst * HD + c0 + 1], v1 + hv.y);
    }
}

// BatchNorm apply from accumulated column sums; optional ReLU
__global__ void bn_k(const float* __restrict__ hl, const float* __restrict__ stats,
                     const float* __restrict__ gam, const float* __restrict__ bet,
                     float* __restrict__ out, int total4, float invN, int relu)
{
    int idx = blockIdx.x * blockDim.x + threadIdx.x;
    if (idx < total4) {
        int c4 = idx & 31;
        float4 x  = ((const float4*)hl)[idx];
        float4 s1 = ((const float4*)stats)[c4];
        float4 s2 = ((const float4*)stats)[32 + c4];
        float4 g  = ((const float4*)gam)[c4];
        float4 b  = ((const float4*)bet)[c4];
        float4 r;
        {
            float m = s1.x * invN; float v = s2.x * invN - m * m;
            r.x = fmaf((x.x - m) * rsqrtf(v + LN_EPS), g.x, b.x);
        }
        {
            float m = s1.y * invN; float v = s2.y * invN - m * m;
            r.y = fmaf((x.y - m) * rsqrtf(v + LN_EPS), g.y, b.y);
        }
        {
            float m = s1.z * invN; float v = s2.z * invN - m * m;
            r.z = fmaf((x.z - m) * rsqrtf(v + LN_EPS), g.z, b.z);
        }
        {
            float m = s1.w * invN; float v = s2.w * invN - m * m;
            r.w = fmaf((x.w - m) * rsqrtf(v + LN_EPS), g.w, b.w);
        }
        if (relu) {
            r.x = fmaxf(r.x, 0.f); r.y = fmaxf(r.y, 0.f);
            r.z = fmaxf(r.z, 0.f); r.w = fmaxf(r.w, 0.f);
        }
        ((float4*)out)[idx] = r;
    }
}

extern "C" void kernel_launch(void* const* d_in, const int* in_sizes, int n_in,
                              void* d_out, int out_size, void* d_ws, size_t ws_size,
                              hipStream_t stream)
{
    const float* x       = (const float*)d_in[0];
    const int*   ei      = (const int*)d_in[1];
    const float* eattr   = (const float*)d_in[2];
    const float* node_W  = (const float*)d_in[3];
    const float* node_b  = (const float*)d_in[4];
    const float* node_g  = (const float*)d_in[5];
    const float* node_be = (const float*)d_in[6];
    const float* edge_W  = (const float*)d_in[7];
    const float* edge_b  = (const float*)d_in[8];
    const float* edge_g  = (const float*)d_in[9];
    const float* edge_be = (const float*)d_in[10];
    const float* sl_attr = (const float*)d_in[11];
    const float* W1      = (const float*)d_in[12];
    const float* b1      = (const float*)d_in[13];
    const float* W2      = (const float*)d_in[14];
    const float* b2      = (const float*)d_in[15];
    const float* bn_g    = (const float*)d_in[16];
    const float* bn_b    = (const float*)d_in[17];

    const int N = in_sizes[0] / NODED;
    const int E = in_sizes[1] / 2;

    float* ws    = (float*)d_ws;
    float* h     = ws;                         // N*128
    float* aggr  = h    + (size_t)N * HD;      // N*128
    float* z     = aggr + (size_t)N * HD;      // N*256 (also node-embed pre-LN buffer)
    float* slv   = z    + (size_t)N * 256;     // 128
    float* stats = slv  + 128;                 // 256
    float* nWt   = stats + 256;                // 64*128
    float* W1t   = nWt  + NODED * HD;          // 3*128*256
    float* W2t   = W1t  + 3 * HD * 256;        // 3*256*128

    // pre-transpose weights to [K][NC]
    transpose_k<<<(HD * NODED + 255) / 256, 256, 0, stream>>>(node_W, nWt, HD, NODED);
    for (int l = 0; l < 3; ++l) {
        transpose_k<<<(256 * HD + 255) / 256, 256, 0, stream>>>(
            W1 + (size_t)l * 256 * HD, W1t + (size_t)l * HD * 256, 256, HD);
        transpose_k<<<(256 * HD + 255) / 256, 256, 0, stream>>>(
            W2 + (size_t)l * HD * 256, W2t + (size_t)l * 256 * HD, HD, 256);
    }

    const int gblocks = (N + 63) / 64;
    const int total4  = N * (HD / 4);
    const int vblocks = (total4 + 255) / 256;

    // node embed: Linear -> LN -> ReLU
    gemm_k<NODED, HD, 0, 0><<<gblocks, 256, 0, stream>>>(x, nWt, node_b, z, N, nullptr);
    ln_relu_k<<<(N + 3) / 4, 256, 0, stream>>>(z, node_g, node_be, h, N);

    for (int l = 0; l < 3; ++l) {
        const float* eW  = edge_W  + (size_t)l * HD * EDGED;
        const float* eb  = edge_b  + l * HD;
        const float* eg  = edge_g  + l * HD;
        const float* ebe = edge_be + l * HD;

        sl_embed_k<<<1, 64, 0, stream>>>(sl_attr + l * EDGED, eW, eb, eg, ebe, slv);
        add_sl_k<<<vblocks, 256, 0, stream>>>(h, slv, aggr, total4);
        edge_k<<<2048, 256, 0, stream>>>(h, ei, eattr, eW, eb, eg, ebe, aggr, E);

        gemm_k<HD, 256, 1, 0><<<gblocks, 256, 0, stream>>>(
            aggr, W1t + (size_t)l * HD * 256, b1 + l * 256, z, N, nullptr);

        hipMemsetAsync(stats, 0, 256 * sizeof(float), stream);
        gemm_k<256, HD, 0, 1><<<gblocks, 256, 0, stream>>>(
            z, W2t + (size_t)l * 256 * HD, b2 + l * HD, (float*)d_out, N, stats);

        bn_k<<<vblocks, 256, 0, stream>>>((const float*)d_out, stats, bn_g + l * HD, bn_b + l * HD,
                                          (l < 2) ? h : (float*)d_out, total4, 1.f / N, (l < 2) ? 1 : 0);
    }
}

// Round 2
// 1637.592 us; speedup vs baseline: 1.7874x; 1.7874x over previous
//
#include <hip/hip_runtime.h>
#include <cstdint>
#include <cstddef>

#define HD 128
#define EDGED 16
#define NODED 64
#define LN_EPS 1e-5f

__device__ __forceinline__ float gelu_exact(float x) {
    return 0.5f * x * (1.0f + erff(x * 0.7071067811865475f));
}

// out[c*R + r] = in[r*C + c]   (in is [R,C] row-major)
__global__ void transpose_k(const float* __restrict__ in, float* __restrict__ out, int R, int C) {
    int idx = blockIdx.x * blockDim.x + threadIdx.x;
    if (idx < R * C) {
        int r = idx / C, c = idx - r * C;
        out[c * R + r] = in[idx];
    }
}

// ---------------- CSR build ----------------

__global__ void hist_k(const int* __restrict__ ei, int* __restrict__ cnt, int E) {
    int e = blockIdx.x * blockDim.x + threadIdx.x;
    if (e < E) atomicAdd(&cnt[ei[E + e]], 1);
}

// per-block exclusive scan of 256 elems, emit block sums
__global__ void scan1_k(const int* __restrict__ in, int* __restrict__ out,
                        int* __restrict__ bsum, int n) {
    __shared__ int lds[256];
    int t = threadIdx.x;
    int i = blockIdx.x * 256 + t;
    int v = (i < n) ? in[i] : 0;
    lds[t] = v;
    __syncthreads();
#pragma unroll
    for (int o = 1; o < 256; o <<= 1) {
        int u = (t >= o) ? lds[t - o] : 0;
        __syncthreads();
        lds[t] += u;
        __syncthreads();
    }
    if (i < n) out[i] = lds[t] - v;
    if (t == 255) bsum[blockIdx.x] = lds[255];
}

// single-block exclusive scan of block sums (nb <= 256)
__global__ void scan2_k(const int* __restrict__ bsum, int* __restrict__ boff, int nb) {
    __shared__ int lds[256];
    int t = threadIdx.x;
    int v = (t < nb) ? bsum[t] : 0;
    lds[t] = v;
    __syncthreads();
#pragma unroll
    for (int o = 1; o < 256; o <<= 1) {
        int u = (t >= o) ? lds[t - o] : 0;
        __syncthreads();
        lds[t] += u;
        __syncthreads();
    }
    if (t < nb) boff[t] = lds[t] - v;
}

__global__ void scan3_k(int* __restrict__ rs, const int* __restrict__ boff, int n, int E) {
    int i = blockIdx.x * 256 + threadIdx.x;
    if (i < n) rs[i] += boff[blockIdx.x];
    if (i == 0) rs[n] = E;
}

// scatter edges into CSR slots: es[slot] = (src, edge_id)
__global__ void scatter_k(const int* __restrict__ ei, int* __restrict__ cursor,
                          int2* __restrict__ es, int E) {
    int e = blockIdx.x * blockDim.x + threadIdx.x;
    if (e < E) {
        int dst = ei[E + e];
        int slot = atomicAdd(&cursor[dst], 1);
        es[slot] = make_int2(ei[e], e);
    }
}

// ---------------- dense GEMM (fp32 vector) ----------------
// C[M,NC] = act(A[M,K] @ Bt[K,NC] + bias), optional fused column sum/sumsq stats.
template<int K, int NC, int ACT, int STATS>
__launch_bounds__(256)
__global__ void gemm_k(const float* __restrict__ A, const float* __restrict__ Bt,
                       const float* __restrict__ bias, float* __restrict__ C,
                       int M, float* __restrict__ stats)
{
    constexpr int CPT = NC / 32;
    constexpr int NB4 = 32 * NC / 1024;
    __shared__ float A_lds[64][36];
    __shared__ float B_lds[32][NC];
    __shared__ float st_lds[2][HD];

    const int t  = threadIdx.x;
    const int cg = t & 31;
    const int ng = t >> 5;
    const int row0 = blockIdx.x * 64;

    float acc[8][CPT];
#pragma unroll
    for (int i = 0; i < 8; ++i)
#pragma unroll
        for (int m = 0; m < CPT; ++m) acc[i][m] = 0.f;

    const int ar  = t >> 2;
    const int akp = (t & 3) * 8;
    const bool arow_ok = (row0 + ar) < M;
    const float* aptr = A + (size_t)(row0 + ar) * K + akp;

    for (int kc = 0; kc < K; kc += 32) {
        float4 a0 = make_float4(0.f, 0.f, 0.f, 0.f), a1 = a0;
        if (arow_ok) {
            const float4* p = (const float4*)(aptr + kc);
            a0 = p[0]; a1 = p[1];
        }
        float4 breg[NB4];
        const float4* Bsrc = (const float4*)(Bt + (size_t)kc * NC);
#pragma unroll
        for (int m = 0; m < NB4; ++m) breg[m] = Bsrc[m * 256 + t];

        __syncthreads();
        *(float4*)&A_lds[ar][akp]     = a0;
        *(float4*)&A_lds[ar][akp + 4] = a1;
#pragma unroll
        for (int m = 0; m < NB4; ++m) {
            int idx = m * 256 + t;
            *(float4*)&((float*)B_lds)[idx * 4] = breg[m];
        }
        __syncthreads();

#pragma unroll 4
        for (int kk = 0; kk < 32; ++kk) {
            float b[CPT];
#pragma unroll
            for (int m = 0; m < CPT; ++m) b[m] = B_lds[kk][cg + 32 * m];
#pragma unroll
            for (int i = 0; i < 8; ++i) {
                float a = A_lds[ng * 8 + i][kk];
#pragma unroll
                for (int m = 0; m < CPT; ++m) acc[i][m] = fmaf(a, b[m], acc[i][m]);
            }
        }
    }

    float bv[CPT];
#pragma unroll
    for (int m = 0; m < CPT; ++m) bv[m] = bias[cg + 32 * m];

    if (STATS) {
        if (t < HD) { st_lds[0][t] = 0.f; st_lds[1][t] = 0.f; }
        __syncthreads();
    }

    float s1[CPT], s2[CPT];
#pragma unroll
    for (int m = 0; m < CPT; ++m) { s1[m] = 0.f; s2[m] = 0.f; }

#pragma unroll
    for (int i = 0; i < 8; ++i) {
        int row = row0 + ng * 8 + i;
        if (row < M) {
#pragma unroll
            for (int m = 0; m < CPT; ++m) {
                float v = acc[i][m] + bv[m];
                if (ACT == 1) v = gelu_exact(v);
                C[(size_t)row * NC + cg + 32 * m] = v;
                if (STATS) { s1[m] += v; s2[m] += v * v; }
            }
        }
    }

    if (STATS) {
#pragma unroll
        for (int m = 0; m < CPT; ++m) {
            atomicAdd(&st_lds[0][cg + 32 * m], s1[m]);
            atomicAdd(&st_lds[1][cg + 32 * m], s2[m]);
        }
        __syncthreads();
        if (t < HD) {
            atomicAdd(&stats[t],      st_lds[0][t]);
            atomicAdd(&stats[HD + t], st_lds[1][t]);
        }
    }
}

// LayerNorm(+ReLU) over rows of 128, one wave per node, 2 cols/lane
__global__ void ln_relu_k(const float* __restrict__ y, const float* __restrict__ gam,
                          const float* __restrict__ bet, float* __restrict__ h, int N)
{
    int lane = threadIdx.x & 63;
    int c0 = lane * 2;
    float2 g2 = *(const float2*)&gam[c0];
    float2 b2 = *(const float2*)&bet[c0];
    int wid = (blockIdx.x * blockDim.x + threadIdx.x) >> 6;
    int nw  = (gridDim.x * blockDim.x) >> 6;
    for (int n = wid; n < N; n += nw) {
        float2 v = *(const float2*)&y[(size_t)n * HD + c0];
        float s = v.x + v.y;
        float q = v.x * v.x + v.y * v.y;
#pragma unroll
        for (int o = 32; o > 0; o >>= 1) { s += __shfl_xor(s, o, 64); q += __shfl_xor(q, o, 64); }
        float mu  = s * (1.f / 128.f);
        float inv = rsqrtf(q * (1.f / 128.f) - mu * mu + LN_EPS);
        float2 r;
        r.x = fmaxf(fmaf((v.x - mu) * inv, g2.x, b2.x), 0.f);
        r.y = fmaxf(fmaf((v.y - mu) * inv, g2.y, b2.y), 0.f);
        *(float2*)&h[(size_t)n * HD + c0] = r;
    }
}

// one wave: embed the single learned self-loop attr -> sl_vec[128]
__global__ void sl_embed_k(const float* __restrict__ attr, const float* __restrict__ W,
                           const float* __restrict__ bias, const float* __restrict__ gam,
                           const float* __restrict__ bet, float* __restrict__ out)
{
    int lane = threadIdx.x;
    int c0 = lane * 2, c1 = c0 + 1;
    float acc0 = bias[c0], acc1 = bias[c1];
    for (int k = 0; k < EDGED; ++k) {
        float a = attr[k];
        acc0 = fmaf(a, W[c0 * EDGED + k], acc0);
        acc1 = fmaf(a, W[c1 * EDGED + k], acc1);
    }
    float s = acc0 + acc1, q = acc0 * acc0 + acc1 * acc1;
#pragma unroll
    for (int o = 32; o > 0; o >>= 1) { s += __shfl_xor(s, o, 64); q += __shfl_xor(q, o, 64); }
    float mu  = s * (1.f / 128.f);
    float inv = rsqrtf(q * (1.f / 128.f) - mu * mu + LN_EPS);
    out[c0] = fmaxf(fmaf((acc0 - mu) * inv, gam[c0], bet[c0]), 0.f);
    out[c1] = fmaxf(fmaf((acc1 - mu) * inv, gam[c1], bet[c1]), 0.f);
}

// ---------------- pull aggregation: one wave per node, no atomics ----------------
// aggr[n] = h[n] + sl_vec + sum_{e in in(n)} ( h[src_e] + ReLU(LN(attr_e @ W^T + b)) )
__launch_bounds__(256)
__global__ void pull_k(const float* __restrict__ h, const int2* __restrict__ es,
                       const int* __restrict__ rs, const float* __restrict__ eattr,
                       const float* __restrict__ slv, const float* __restrict__ W,
                       const float* __restrict__ bias, const float* __restrict__ gam,
                       const float* __restrict__ bet, float* __restrict__ aggr, int N)
{
    __shared__ float Wt[EDGED * HD];   // [k][c]
    const int t = threadIdx.x;
#pragma unroll
    for (int m = 0; m < EDGED * HD / 256; ++m) {
        int idx = m * 256 + t;
        int c = idx >> 4, k = idx & 15;
        Wt[k * HD + c] = W[idx];
    }
    const int lane = t & 63;
    const int c0 = lane * 2;
    const float2 b2 = *(const float2*)&bias[c0];
    const float2 g2 = *(const float2*)&gam[c0];
    const float2 e2 = *(const float2*)&bet[c0];
    const float2 sl = *(const float2*)&slv[c0];
    __syncthreads();

    const int n = (blockIdx.x * 256 + t) >> 6;
    if (n >= N) return;

    float2 acc = *(const float2*)&h[(size_t)n * HD + c0];
    acc.x += sl.x; acc.y += sl.y;

    const int beg = rs[n], end = rs[n + 1];
    for (int s0 = beg; s0 < end; s0 += 64) {
        int m = end - s0; if (m > 64) m = 64;
        int2 se = (lane < m) ? es[s0 + lane] : make_int2(0, 0);
        // prefetch attr of edge 0
        int eid0 = __shfl(se.y, 0, 64);
        float av = (lane < EDGED) ? eattr[(size_t)eid0 * EDGED + lane] : 0.f;
        for (int j = 0; j < m; ++j) {
            float avc = av;
            if (j + 1 < m) {
                int eidn = __shfl(se.y, j + 1, 64);
                av = (lane < EDGED) ? eattr[(size_t)eidn * EDGED + lane] : 0.f;
            }
            int src = __shfl(se.x, j, 64);
            float2 hv = *(const float2*)&h[(size_t)src * HD + c0];
            float a0 = b2.x, a1 = b2.y;
#pragma unroll
            for (int k = 0; k < EDGED; ++k) {
                float ak = __shfl(avc, k, 64);
                float2 w = *(const float2*)&Wt[k * HD + c0];
                a0 = fmaf(ak, w.x, a0);
                a1 = fmaf(ak, w.y, a1);
            }
            float su = a0 + a1;
            float q  = fmaf(a0, a0, a1 * a1);
#pragma unroll
            for (int o = 32; o > 0; o >>= 1) { su += __shfl_xor(su, o, 64); q += __shfl_xor(q, o, 64); }
            float mu  = su * (1.f / 128.f);
            float inv = rsqrtf(q * (1.f / 128.f) - mu * mu + LN_EPS);
            float v0 = fmaxf(fmaf((a0 - mu) * inv, g2.x, e2.x), 0.f);
            float v1 = fmaxf(fmaf((a1 - mu) * inv, g2.y, e2.y), 0.f);
            acc.x += v0 + hv.x;
            acc.y += v1 + hv.y;
        }
    }
    *(float2*)&aggr[(size_t)n * HD + c0] = acc;
}

// BatchNorm apply from accumulated column sums; optional ReLU
__global__ void bn_k(const float* __restrict__ hl, const float* __restrict__ stats,
                     const float* __restrict__ gam, const float* __restrict__ bet,
                     float* __restrict__ out, int total4, float invN, int relu)
{
    int idx = blockIdx.x * blockDim.x + threadIdx.x;
    if (idx < total4) {
        int c4 = idx & 31;
        float4 x  = ((const float4*)hl)[idx];
        float4 s1 = ((const float4*)stats)[c4];
        float4 s2 = ((const float4*)stats)[32 + c4];
        float4 g  = ((const float4*)gam)[c4];
        float4 b  = ((const float4*)bet)[c4];
        float4 r;
        {
            float m = s1.x * invN; float v = s2.x * invN - m * m;
            r.x = fmaf((x.x - m) * rsqrtf(v + LN_EPS), g.x, b.x);
        }
        {
            float m = s1.y * invN; float v = s2.y * invN - m * m;
            r.y = fmaf((x.y - m) * rsqrtf(v + LN_EPS), g.y, b.y);
        }
        {
            float m = s1.z * invN; float v = s2.z * invN - m * m;
            r.z = fmaf((x.z - m) * rsqrtf(v + LN_EPS), g.z, b.z);
        }
        {
            float m = s1.w * invN; float v = s2.w * invN - m * m;
            r.w = fmaf((x.w - m) * rsqrtf(v + LN_EPS), g.w, b.w);
        }
        if (relu) {
            r.x = fmaxf(r.x, 0.f); r.y = fmaxf(r.y, 0.f);
            r.z = fmaxf(r.z, 0.f); r.w = fmaxf(r.w, 0.f);
        }
        ((float4*)out)[idx] = r;
    }
}

extern "C" void kernel_launch(void* const* d_in, const int* in_sizes, int n_in,
                              void* d_out, int out_size, void* d_ws, size_t ws_size,
                              hipStream_t stream)
{
    const float* x       = (const float*)d_in[0];
    const int*   ei      = (const int*)d_in[1];
    const float* eattr   = (const float*)d_in[2];
    const float* node_W  = (const float*)d_in[3];
    const float* node_b  = (const float*)d_in[4];
    const float* node_g  = (const float*)d_in[5];
    const float* node_be = (const float*)d_in[6];
    const float* edge_W  = (const float*)d_in[7];
    const float* edge_b  = (const float*)d_in[8];
    const float* edge_g  = (const float*)d_in[9];
    const float* edge_be = (const float*)d_in[10];
    const float* sl_attr = (const float*)d_in[11];
    const float* W1      = (const float*)d_in[12];
    const float* b1      = (const float*)d_in[13];
    const float* W2      = (const float*)d_in[14];
    const float* b2      = (const float*)d_in[15];
    const float* bn_g    = (const float*)d_in[16];
    const float* bn_b    = (const float*)d_in[17];

    const int N = in_sizes[0] / NODED;
    const int E = in_sizes[1] / 2;

    float* ws    = (float*)d_ws;
    float* h     = ws;                         // N*128
    float* aggr  = h    + (size_t)N * HD;      // N*128
    float* z     = aggr + (size_t)N * HD;      // N*256
    float* slv   = z    + (size_t)N * 256;     // 128
    float* stats = slv  + 128;                 // 256
    float* nWt   = stats + 256;                // 64*128
    float* W1t   = nWt  + NODED * HD;          // 3*128*256
    float* W2t   = W1t  + 3 * HD * 256;        // 3*256*128
    int*   cnt    = (int*)(W2t + 3 * 256 * HD);  // N
    int*   cursor = cnt + N;                     // N
    int*   bsum   = cursor + N;                  // 256
    int*   boff   = bsum + 256;                  // 256
    int*   rs     = boff + 256;                  // N+1 (+1 pad)
    int2*  es     = (int2*)(rs + N + 2);         // E  (8B aligned: N even)

    // pre-transpose weights to [K][NC]
    transpose_k<<<(HD * NODED + 255) / 256, 256, 0, stream>>>(node_W, nWt, HD, NODED);
    for (int l = 0; l < 3; ++l) {
        transpose_k<<<(256 * HD + 255) / 256, 256, 0, stream>>>(
            W1 + (size_t)l * 256 * HD, W1t + (size_t)l * HD * 256, 256, HD);
        transpose_k<<<(256 * HD + 255) / 256, 256, 0, stream>>>(
            W2 + (size_t)l * HD * 256, W2t + (size_t)l * 256 * HD, HD, 256);
    }

    // ---- CSR build (edge_index constant across layers) ----
    const int eblocks = (E + 255) / 256;
    const int nblocks = (N + 255) / 256;
    hipMemsetAsync(cnt, 0, (size_t)N * sizeof(int), stream);
    hist_k<<<eblocks, 256, 0, stream>>>(ei, cnt, E);
    scan1_k<<<nblocks, 256, 0, stream>>>(cnt, rs, bsum, N);
    scan2_k<<<1, 256, 0, stream>>>(bsum, boff, nblocks);
    scan3_k<<<nblocks, 256, 0, stream>>>(rs, boff, N, E);
    hipMemcpyAsync(cursor, rs, (size_t)N * sizeof(int), hipMemcpyDeviceToDevice, stream);
    scatter_k<<<eblocks, 256, 0, stream>>>(ei, cursor, es, E);

    const int gblocks = (N + 63) / 64;
    const int total4  = N * (HD / 4);
    const int vblocks = (total4 + 255) / 256;
    const int pblocks = (N + 3) / 4;

    // node embed: Linear -> LN -> ReLU
    gemm_k<NODED, HD, 0, 0><<<gblocks, 256, 0, stream>>>(x, nWt, node_b, z, N, nullptr);
    ln_relu_k<<<pblocks, 256, 0, stream>>>(z, node_g, node_be, h, N);

    for (int l = 0; l < 3; ++l) {
        const float* eW  = edge_W  + (size_t)l * HD * EDGED;
        const float* eb  = edge_b  + l * HD;
        const float* eg  = edge_g  + l * HD;
        const float* ebe = edge_be + l * HD;

        sl_embed_k<<<1, 64, 0, stream>>>(sl_attr + l * EDGED, eW, eb, eg, ebe, slv);
        pull_k<<<pblocks, 256, 0, stream>>>(h, es, rs, eattr, slv, eW, eb, eg, ebe, aggr, N);

        gemm_k<HD, 256, 1, 0><<<gblocks, 256, 0, stream>>>(
            aggr, W1t + (size_t)l * HD * 256, b1 + l * 256, z, N, nullptr);

        hipMemsetAsync(stats, 0, 256 * sizeof(float), stream);
        gemm_k<256, HD, 0, 1><<<gblocks, 256, 0, stream>>>(
            z, W2t + (size_t)l * 256 * HD, b2 + l * HD, (float*)d_out, N, stats);

        bn_k<<<vblocks, 256, 0, stream>>>((const float*)d_out, stats, bn_g + l * HD, bn_b + l * HD,
                                          (l < 2) ? h : (float*)d_out, total4, 1.f / N, (l < 2) ? 1 : 0);
    }
}

// Round 4
// 1178.855 us; speedup vs baseline: 2.4829x; 1.3891x over previous
//
#include <hip/hip_runtime.h>
#include <cstdint>
#include <cstddef>

#define HD 128
#define EDGED 16
#define NODED 64
#define LN_EPS 1e-5f

__device__ __forceinline__ float gelu_exact(float x) {
    return 0.5f * x * (1.0f + erff(x * 0.7071067811865475f));
}

// out[c*R + r] = in[r*C + c]   (in is [R,C] row-major)
__global__ void transpose_k(const float* __restrict__ in, float* __restrict__ out, int R, int C) {
    int idx = blockIdx.x * blockDim.x + threadIdx.x;
    if (idx < R * C) {
        int r = idx / C, c = idx - r * C;
        out[c * R + r] = in[idx];
    }
}

// ---------------- CSR build ----------------

__global__ void hist_k(const int* __restrict__ ei, int* __restrict__ cnt, int E) {
    int e = blockIdx.x * blockDim.x + threadIdx.x;
    if (e < E) atomicAdd(&cnt[ei[E + e]], 1);
}

__global__ void scan1_k(const int* __restrict__ in, int* __restrict__ out,
                        int* __restrict__ bsum, int n) {
    __shared__ int lds[256];
    int t = threadIdx.x;
    int i = blockIdx.x * 256 + t;
    int v = (i < n) ? in[i] : 0;
    lds[t] = v;
    __syncthreads();
#pragma unroll
    for (int o = 1; o < 256; o <<= 1) {
        int u = (t >= o) ? lds[t - o] : 0;
        __syncthreads();
        lds[t] += u;
        __syncthreads();
    }
    if (i < n) out[i] = lds[t] - v;
    if (t == 255) bsum[blockIdx.x] = lds[255];
}

__global__ void scan2_k(const int* __restrict__ bsum, int* __restrict__ boff, int nb) {
    __shared__ int lds[256];
    int t = threadIdx.x;
    int v = (t < nb) ? bsum[t] : 0;
    lds[t] = v;
    __syncthreads();
#pragma unroll
    for (int o = 1; o < 256; o <<= 1) {
        int u = (t >= o) ? lds[t - o] : 0;
        __syncthreads();
        lds[t] += u;
        __syncthreads();
    }
    if (t < nb) boff[t] = lds[t] - v;
}

__global__ void scan3_k(int* __restrict__ rs, const int* __restrict__ boff, int n, int E) {
    int i = blockIdx.x * 256 + threadIdx.x;
    if (i < n) rs[i] += boff[blockIdx.x];
    if (i == 0) rs[n] = E;
}

__global__ void scatter_k(const int* __restrict__ ei, int* __restrict__ cursor,
                          int2* __restrict__ es, int E) {
    int e = blockIdx.x * blockDim.x + threadIdx.x;
    if (e < E) {
        int dst = ei[E + e];
        int slot = atomicAdd(&cursor[dst], 1);
        es[slot] = make_int2(ei[e], e);
    }
}

// ---------------- edge-LN precompute ----------------
// Per layer l: wm[k]=mean_c W[c][k]; bm=mean(b); Wp=W-wm; bp=b-bm.
// Wg[k][c] = Wp[c][k]*g[c]; bg[c] = bp[c]*g[c]
// M[k][j]  = sum_c Wp[c][k]*Wp[c][j];  v[k]=2*sum_c Wp[c][k]*bp[c];  s0=sum bp^2
// => 128*var(attr a) = a^T M a + v.a + s0 (no 128-wide reduce per edge).
__global__ void prep_k(const float* __restrict__ edge_W, const float* __restrict__ edge_b,
                       const float* __restrict__ edge_g, float* __restrict__ Wg3,
                       float* __restrict__ bg3, float* __restrict__ M3,
                       float* __restrict__ v3, float* __restrict__ s03)
{
    const int l = blockIdx.x;
    const float* W = edge_W + (size_t)l * HD * EDGED;
    const float* b = edge_b + l * HD;
    const float* g = edge_g + l * HD;
    __shared__ float Wp[HD * EDGED];
    __shared__ float bp[HD];
    __shared__ float wm[EDGED];
    __shared__ float bmS;
    const int t = threadIdx.x;
#pragma unroll
    for (int m = 0; m < 8; ++m) Wp[m * 256 + t] = W[m * 256 + t];
    __syncthreads();
    if (t < EDGED) {
        float s = 0.f;
        for (int c = 0; c < HD; ++c) s += Wp[c * EDGED + t];
        wm[t] = s * (1.f / HD);
    } else if (t == EDGED) {
        float s = 0.f;
        for (int c = 0; c < HD; ++c) s += b[c];
        bmS = s * (1.f / HD);
    }
    __syncthreads();
    if (t < HD) bp[t] = b[t] - bmS;
    __syncthreads();
#pragma unroll
    for (int m = 0; m < 8; ++m) {
        int idx = m * 256 + t;
        int c = idx >> 4, k = idx & 15;
        float val = Wp[idx] - wm[k];
        Wp[idx] = val;
        Wg3[(size_t)l * 2048 + k * HD + c] = val * g[c];
    }
    if (t < HD) bg3[l * HD + t] = bp[t] * g[t];
    __syncthreads();
    {
        int k = t >> 4, j = t & 15;
        float s = 0.f;
        for (int c = 0; c < HD; ++c) s += Wp[c * EDGED + k] * Wp[c * EDGED + j];
        M3[l * 256 + t] = s;
    }
    if (t < EDGED) {
        float s = 0.f;
        for (int c = 0; c < HD; ++c) s += Wp[c * EDGED + t] * bp[c];
        v3[l * EDGED + t] = 2.f * s;
    } else if (t == EDGED) {
        float s = 0.f;
        for (int c = 0; c < HD; ++c) s += bp[c] * bp[c];
        s03[l] = s;
    }
}

// Per CSR slot: gather attr row once, emit rsqrt(var+eps) for all 3 layers
__launch_bounds__(256)
__global__ void einv_k(const int2* __restrict__ es, const float* __restrict__ eattr,
                       const float* __restrict__ M3, const float* __restrict__ v3,
                       const float* __restrict__ s03, float* __restrict__ einv, int E)
{
    __shared__ float Ms[3 * 256];
    __shared__ float vs[3 * 16];
    __shared__ float s0s[4];
    const int t = threadIdx.x;
    for (int i = t; i < 768; i += 256) Ms[i] = M3[i];
    if (t < 48) vs[t] = v3[t];
    if (t < 3) s0s[t] = s03[t];
    __syncthreads();
    int slot = blockIdx.x * 256 + t;
    if (slot >= E) return;
    int eid = es[slot].y;
    const float4* ap = (const float4*)(eattr + (size_t)eid * EDGED);
    float4 A0 = ap[0], A1 = ap[1], A2 = ap[2], A3 = ap[3];
    float a[16] = {A0.x, A0.y, A0.z, A0.w, A1.x, A1.y, A1.z, A1.w,
                   A2.x, A2.y, A2.z, A2.w, A3.x, A3.y, A3.z, A3.w};
#pragma unroll
    for (int l = 0; l < 3; ++l) {
        float q = s0s[l];
#pragma unroll
        for (int k = 0; k < 16; ++k) {
            const float* Mr = &Ms[l * 256 + k * 16];
            float tk = vs[l * 16 + k];
#pragma unroll
            for (int j = 0; j < 16; ++j) tk = fmaf(Mr[j], a[j], tk);
            q = fmaf(a[k], tk, q);
        }
        einv[(size_t)l * E + slot] = rsqrtf(q * (1.f / HD) + LN_EPS);
    }
}

// ---------------- dense GEMM (fp32 vector) ----------------
template<int K, int NC, int ACT, int STATS>
__launch_bounds__(256)
__global__ void gemm_k(const float* __restrict__ A, const float* __restrict__ Bt,
                       const float* __restrict__ bias, float* __restrict__ C,
                       int M, float* __restrict__ stats)
{
    constexpr int CPT = NC / 32;
    constexpr int NB4 = 32 * NC / 1024;
    __shared__ float A_lds[64][36];
    __shared__ float B_lds[32][NC];
    __shared__ float st_lds[2][HD];

    const int t  = threadIdx.x;
    const int cg = t & 31;
    const int ng = t >> 5;
    const int row0 = blockIdx.x * 64;

    float acc[8][CPT];
#pragma unroll
    for (int i = 0; i < 8; ++i)
#pragma unroll
        for (int m = 0; m < CPT; ++m) acc[i][m] = 0.f;

    const int ar  = t >> 2;
    const int akp = (t & 3) * 8;
    const bool arow_ok = (row0 + ar) < M;
    const float* aptr = A + (size_t)(row0 + ar) * K + akp;

    for (int kc = 0; kc < K; kc += 32) {
        float4 a0 = make_float4(0.f, 0.f, 0.f, 0.f), a1 = a0;
        if (arow_ok) {
            const float4* p = (const float4*)(aptr + kc);
            a0 = p[0]; a1 = p[1];
        }
        float4 breg[NB4];
        const float4* Bsrc = (const float4*)(Bt + (size_t)kc * NC);
#pragma unroll
        for (int m = 0; m < NB4; ++m) breg[m] = Bsrc[m * 256 + t];

        __syncthreads();
        *(float4*)&A_lds[ar][akp]     = a0;
        *(float4*)&A_lds[ar][akp + 4] = a1;
#pragma unroll
        for (int m = 0; m < NB4; ++m) {
            int idx = m * 256 + t;
            *(float4*)&((float*)B_lds)[idx * 4] = breg[m];
        }
        __syncthreads();

#pragma unroll 4
        for (int kk = 0; kk < 32; ++kk) {
            float b[CPT];
#pragma unroll
            for (int m = 0; m < CPT; ++m) b[m] = B_lds[kk][cg + 32 * m];
#pragma unroll
            for (int i = 0; i < 8; ++i) {
                float a = A_lds[ng * 8 + i][kk];
#pragma unroll
                for (int m = 0; m < CPT; ++m) acc[i][m] = fmaf(a, b[m], acc[i][m]);
            }
        }
    }

    float bv[CPT];
#pragma unroll
    for (int m = 0; m < CPT; ++m) bv[m] = bias[cg + 32 * m];

    if (STATS) {
        if (t < HD) { st_lds[0][t] = 0.f; st_lds[1][t] = 0.f; }
        __syncthreads();
    }

    float s1[CPT], s2[CPT];
#pragma unroll
    for (int m = 0; m < CPT; ++m) { s1[m] = 0.f; s2[m] = 0.f; }

#pragma unroll
    for (int i = 0; i < 8; ++i) {
        int row = row0 + ng * 8 + i;
        if (row < M) {
#pragma unroll
            for (int m = 0; m < CPT; ++m) {
                float v = acc[i][m] + bv[m];
                if (ACT == 1) v = gelu_exact(v);
                C[(size_t)row * NC + cg + 32 * m] = v;
                if (STATS) { s1[m] += v; s2[m] += v * v; }
            }
        }
    }

    if (STATS) {
#pragma unroll
        for (int m = 0; m < CPT; ++m) {
            atomicAdd(&st_lds[0][cg + 32 * m], s1[m]);
            atomicAdd(&st_lds[1][cg + 32 * m], s2[m]);
        }
        __syncthreads();
        if (t < HD) {
            atomicAdd(&stats[t],      st_lds[0][t]);
            atomicAdd(&stats[HD + t], st_lds[1][t]);
        }
    }
}

// LayerNorm(+ReLU) over rows of 128, one wave per node
__global__ void ln_relu_k(const float* __restrict__ y, const float* __restrict__ gam,
                          const float* __restrict__ bet, float* __restrict__ h, int N)
{
    int lane = threadIdx.x & 63;
    int c0 = lane * 2;
    float2 g2 = *(const float2*)&gam[c0];
    float2 b2 = *(const float2*)&bet[c0];
    int wid = (blockIdx.x * blockDim.x + threadIdx.x) >> 6;
    int nw  = (gridDim.x * blockDim.x) >> 6;
    for (int n = wid; n < N; n += nw) {
        float2 v = *(const float2*)&y[(size_t)n * HD + c0];
        float s = v.x + v.y;
        float q = v.x * v.x + v.y * v.y;
#pragma unroll
        for (int o = 32; o > 0; o >>= 1) { s += __shfl_xor(s, o, 64); q += __shfl_xor(q, o, 64); }
        float mu  = s * (1.f / 128.f);
        float inv = rsqrtf(q * (1.f / 128.f) - mu * mu + LN_EPS);
        float2 r;
        r.x = fmaxf(fmaf((v.x - mu) * inv, g2.x, b2.x), 0.f);
        r.y = fmaxf(fmaf((v.y - mu) * inv, g2.y, b2.y), 0.f);
        *(float2*)&h[(size_t)n * HD + c0] = r;
    }
}

// one wave: embed the single learned self-loop attr -> sl_vec[128]
__global__ void sl_embed_k(const float* __restrict__ attr, const float* __restrict__ W,
                           const float* __restrict__ bias, const float* __restrict__ gam,
                           const float* __restrict__ bet, float* __restrict__ out)
{
    int lane = threadIdx.x;
    int c0 = lane * 2, c1 = c0 + 1;
    float acc0 = bias[c0], acc1 = bias[c1];
    for (int k = 0; k < EDGED; ++k) {
        float a = attr[k];
        acc0 = fmaf(a, W[c0 * EDGED + k], acc0);
        acc1 = fmaf(a, W[c1 * EDGED + k], acc1);
    }
    float s = acc0 + acc1, q = acc0 * acc0 + acc1 * acc1;
#pragma unroll
    for (int o = 32; o > 0; o >>= 1) { s += __shfl_xor(s, o, 64); q += __shfl_xor(q, o, 64); }
    float mu  = s * (1.f / 128.f);
    float inv = rsqrtf(q * (1.f / 128.f) - mu * mu + LN_EPS);
    out[c0] = fmaxf(fmaf((acc0 - mu) * inv, gam[c0], bet[c0]), 0.f);
    out[c1] = fmaxf(fmaf((acc1 - mu) * inv, gam[c1], bet[c1]), 0.f);
}

// ---------------- pull aggregation v3: reg weights, no per-edge reductions ----
// lane owns channels {lane, lane+64}; edge-embed weights in VGPRs; attr chunk
// staged in per-wave LDS; LN var via precomputed einv.
// NOTE: all __shfl must execute at FULL wave exec (bpermute from an inactive
// lane is undefined) — shfls are hoisted out of predicated code.
__launch_bounds__(256)
__global__ void pull3_k(const float* __restrict__ h, const int2* __restrict__ es,
                        const int* __restrict__ rs, const float* __restrict__ eattr,
                        const float* __restrict__ einv, const float* __restrict__ slv,
                        const float* __restrict__ Wg, const float* __restrict__ bg,
                        const float* __restrict__ bet, float* __restrict__ aggr, int N)
{
    __shared__ float alds_all[4][64 * EDGED];   // 16 KB: per-wave attr staging
    const int t = threadIdx.x;
    const int lane = t & 63;
    const int wv = t >> 6;
    float* alds = alds_all[wv];

    const int c1 = lane, c2 = lane + 64;
    float w1[16], w2[16];
#pragma unroll
    for (int k = 0; k < 16; ++k) {
        w1[k] = Wg[k * HD + c1];
        w2[k] = Wg[k * HD + c2];
    }
    const float bg1 = bg[c1], bg2 = bg[c2];
    const float bt1 = bet[c1], bt2 = bet[c2];

    const int n = (blockIdx.x << 2) + wv;
    if (n >= N) return;

    float acc1 = h[(size_t)n * HD + c1] + slv[c1];
    float acc2 = h[(size_t)n * HD + c2] + slv[c2];

    const int beg = rs[n], end = rs[n + 1];
    for (int s0 = beg; s0 < end; s0 += 64) {
        int m = end - s0; if (m > 64) m = 64;
        int2 se = make_int2(0, 0);
        float iv = 0.f;
        if (lane < m) { se = es[s0 + lane]; iv = einv[s0 + lane]; }
        // stage attrs: fixed 4 iterations; shfl at full exec (jsrc always a
        // valid lane id 0..63); memory ops predicated on idx < 4m.
#pragma unroll
        for (int it = 0; it < 4; ++it) {
            int idx  = (it << 6) + lane;
            int jsrc = idx >> 2;                       // 0..63
            int eid  = __shfl(se.y, jsrc, 64);         // full-exec shfl
            if (idx < (m << 2)) {
                float4 av = *(const float4*)&eattr[(size_t)eid * EDGED + ((idx & 3) << 2)];
                *(float4*)&alds[idx << 2] = av;
            }
        }
        asm volatile("s_waitcnt lgkmcnt(0)" ::: "memory");
        for (int j = 0; j < m; ++j) {
            float4 A0 = *(const float4*)&alds[j * EDGED];
            float4 A1 = *(const float4*)&alds[j * EDGED + 4];
            float4 A2 = *(const float4*)&alds[j * EDGED + 8];
            float4 A3 = *(const float4*)&alds[j * EDGED + 12];
            int   src = __shfl(se.x, j, 64);
            float ivj = __shfl(iv,   j, 64);
            float hv1 = h[(size_t)src * HD + c1];
            float hv2 = h[(size_t)src * HD + c2];
            float a[16] = {A0.x, A0.y, A0.z, A0.w, A1.x, A1.y, A1.z, A1.w,
                           A2.x, A2.y, A2.z, A2.w, A3.x, A3.y, A3.z, A3.w};
            float p1 = bg1, q1 = 0.f, p2 = bg2, q2 = 0.f;
#pragma unroll
            for (int k = 0; k < 16; k += 2) {
                p1 = fmaf(a[k],     w1[k],     p1);
                q1 = fmaf(a[k + 1], w1[k + 1], q1);
                p2 = fmaf(a[k],     w2[k],     p2);
                q2 = fmaf(a[k + 1], w2[k + 1], q2);
            }
            float v1 = fmaxf(fmaf(p1 + q1, ivj, bt1), 0.f);
            float v2 = fmaxf(fmaf(p2 + q2, ivj, bt2), 0.f);
            acc1 += v1 + hv1;
            acc2 += v2 + hv2;
        }
    }
    aggr[(size_t)n * HD + c1] = acc1;
    aggr[(size_t)n * HD + c2] = acc2;
}

// BatchNorm apply from accumulated column sums; optional ReLU
__global__ void bn_k(const float* __restrict__ hl, const float* __restrict__ stats,
                     const float* __restrict__ gam, const float* __restrict__ bet,
                     float* __restrict__ out, int total4, float invN, int relu)
{
    int idx = blockIdx.x * blockDim.x + threadIdx.x;
    if (idx < total4) {
        int c4 = idx & 31;
        float4 x  = ((const float4*)hl)[idx];
        float4 s1 = ((const float4*)stats)[c4];
        float4 s2 = ((const float4*)stats)[32 + c4];
        float4 g  = ((const float4*)gam)[c4];
        float4 b  = ((const float4*)bet)[c4];
        float4 r;
        {
            float m = s1.x * invN; float v = s2.x * invN - m * m;
            r.x = fmaf((x.x - m) * rsqrtf(v + LN_EPS), g.x, b.x);
        }
        {
            float m = s1.y * invN; float v = s2.y * invN - m * m;
            r.y = fmaf((x.y - m) * rsqrtf(v + LN_EPS), g.y, b.y);
        }
        {
            float m = s1.z * invN; float v = s2.z * invN - m * m;
            r.z = fmaf((x.z - m) * rsqrtf(v + LN_EPS), g.z, b.z);
        }
        {
            float m = s1.w * invN; float v = s2.w * invN - m * m;
            r.w = fmaf((x.w - m) * rsqrtf(v + LN_EPS), g.w, b.w);
        }
        if (relu) {
            r.x = fmaxf(r.x, 0.f); r.y = fmaxf(r.y, 0.f);
            r.z = fmaxf(r.z, 0.f); r.w = fmaxf(r.w, 0.f);
        }
        ((float4*)out)[idx] = r;
    }
}

extern "C" void kernel_launch(void* const* d_in, const int* in_sizes, int n_in,
                              void* d_out, int out_size, void* d_ws, size_t ws_size,
                              hipStream_t stream)
{
    const float* x       = (const float*)d_in[0];
    const int*   ei      = (const int*)d_in[1];
    const float* eattr   = (const float*)d_in[2];
    const float* node_W  = (const float*)d_in[3];
    const float* node_b  = (const float*)d_in[4];
    const float* node_g  = (const float*)d_in[5];
    const float* node_be = (const float*)d_in[6];
    const float* edge_W  = (const float*)d_in[7];
    const float* edge_b  = (const float*)d_in[8];
    const float* edge_g  = (const float*)d_in[9];
    const float* edge_be = (const float*)d_in[10];
    const float* sl_attr = (const float*)d_in[11];
    const float* W1      = (const float*)d_in[12];
    const float* b1      = (const float*)d_in[13];
    const float* W2      = (const float*)d_in[14];
    const float* b2      = (const float*)d_in[15];
    const float* bn_g    = (const float*)d_in[16];
    const float* bn_b    = (const float*)d_in[17];

    const int N = in_sizes[0] / NODED;
    const int E = in_sizes[1] / 2;

    float* ws    = (float*)d_ws;
    float* h     = ws;                         // N*128
    float* aggr  = h    + (size_t)N * HD;      // N*128
    float* z     = aggr + (size_t)N * HD;      // N*256
    float* slv   = z    + (size_t)N * 256;     // 128
    float* stats = slv  + 128;                 // 256
    float* nWt   = stats + 256;                // 64*128
    float* W1t   = nWt  + NODED * HD;          // 3*128*256
    float* W2t   = W1t  + 3 * HD * 256;        // 3*256*128
    int*   cnt    = (int*)(W2t + 3 * 256 * HD);  // N
    int*   cursor = cnt + N;                     // N
    int*   bsum   = cursor + N;                  // 256
    int*   boff   = bsum + 256;                  // 256
    int*   rs     = boff + 256;                  // N+2
    int2*  es     = (int2*)(rs + N + 2);         // E (8B aligned)
    float* einv   = (float*)(es + E);            // 3*E
    float* Wg3    = einv + (size_t)3 * E;        // 3*2048
    float* bg3    = Wg3 + 3 * 2048;              // 3*128
    float* M3     = bg3 + 3 * 128;               // 3*256
    float* v3     = M3 + 3 * 256;                // 3*16
    float* s03    = v3 + 3 * 16;                 // 3

    // pre-transpose weights to [K][NC]
    transpose_k<<<(HD * NODED + 255) / 256, 256, 0, stream>>>(node_W, nWt, HD, NODED);
    for (int l = 0; l < 3; ++l) {
        transpose_k<<<(256 * HD + 255) / 256, 256, 0, stream>>>(
            W1 + (size_t)l * 256 * HD, W1t + (size_t)l * HD * 256, 256, HD);
        transpose_k<<<(256 * HD + 255) / 256, 256, 0, stream>>>(
            W2 + (size_t)l * HD * 256, W2t + (size_t)l * 256 * HD, HD, 256);
    }

    // edge-LN precompute (all 3 layers)
    prep_k<<<3, 256, 0, stream>>>(edge_W, edge_b, edge_g, Wg3, bg3, M3, v3, s03);

    // ---- CSR build ----
    const int eblocks = (E + 255) / 256;
    const int nblocks = (N + 255) / 256;
    hipMemsetAsync(cnt, 0, (size_t)N * sizeof(int), stream);
    hist_k<<<eblocks, 256, 0, stream>>>(ei, cnt, E);
    scan1_k<<<nblocks, 256, 0, stream>>>(cnt, rs, bsum, N);
    scan2_k<<<1, 256, 0, stream>>>(bsum, boff, nblocks);
    scan3_k<<<nblocks, 256, 0, stream>>>(rs, boff, N, E);
    hipMemcpyAsync(cursor, rs, (size_t)N * sizeof(int), hipMemcpyDeviceToDevice, stream);
    scatter_k<<<eblocks, 256, 0, stream>>>(ei, cursor, es, E);

    // per-slot inv-std for all 3 layers (one attr gather)
    einv_k<<<eblocks, 256, 0, stream>>>(es, eattr, M3, v3, s03, einv, E);

    const int gblocks = (N + 63) / 64;
    const int total4  = N * (HD / 4);
    const int vblocks = (total4 + 255) / 256;
    const int pblocks = (N + 3) / 4;

    // node embed: Linear -> LN -> ReLU
    gemm_k<NODED, HD, 0, 0><<<gblocks, 256, 0, stream>>>(x, nWt, node_b, z, N, nullptr);
    ln_relu_k<<<pblocks, 256, 0, stream>>>(z, node_g, node_be, h, N);

    for (int l = 0; l < 3; ++l) {
        const float* eW  = edge_W  + (size_t)l * HD * EDGED;
        const float* eb  = edge_b  + l * HD;
        const float* eg  = edge_g  + l * HD;
        const float* ebe = edge_be + l * HD;

        sl_embed_k<<<1, 64, 0, stream>>>(sl_attr + l * EDGED, eW, eb, eg, ebe, slv);
        pull3_k<<<pblocks, 256, 0, stream>>>(h, es, rs, eattr, einv + (size_t)l * E, slv,
                                             Wg3 + (size_t)l * 2048, bg3 + l * HD,
                                             ebe, aggr, N);

        gemm_k<HD, 256, 1, 0><<<gblocks, 256, 0, stream>>>(
            aggr, W1t + (size_t)l * HD * 256, b1 + l * 256, z, N, nullptr);

        hipMemsetAsync(stats, 0, 256 * sizeof(float), stream);
        gemm_k<256, HD, 0, 1><<<gblocks, 256, 0, stream>>>(
            z, W2t + (size_t)l * 256 * HD, b2 + l * HD, (float*)d_out, N, stats);

        bn_k<<<vblocks, 256, 0, stream>>>((const float*)d_out, stats, bn_g + l * HD, bn_b + l * HD,
                                          (l < 2) ? h : (float*)d_out, total4, 1.f / N, (l < 2) ? 1 : 0);
    }
}

// Round 5
// 1049.414 us; speedup vs baseline: 2.7891x; 1.1233x over previous
//
#include <hip/hip_runtime.h>
#include <cstdint>
#include <cstddef>

#define HD 128
#define EDGED 16
#define NODED 64
#define LN_EPS 1e-5f

typedef __bf16 bf16x8 __attribute__((ext_vector_type(8)));
typedef float  f32x4  __attribute__((ext_vector_type(4)));

__device__ __forceinline__ float gelu_exact(float x) {
    return 0.5f * x * (1.0f + erff(x * 0.7071067811865475f));
}

// fp32 -> bf16 hi/lo split (a ~= hi + lo, lo captures the rounding residual)
__global__ void wconv_k(const float* __restrict__ in, __bf16* __restrict__ hi,
                        __bf16* __restrict__ lo, int n) {
    int i = blockIdx.x * blockDim.x + threadIdx.x;
    if (i < n) {
        float v = in[i];
        __bf16 h = (__bf16)v;
        hi[i] = h;
        lo[i] = (__bf16)(v - (float)h);
    }
}

// ---------------- CSR build ----------------

__global__ void hist_k(const int* __restrict__ ei, int* __restrict__ cnt, int E) {
    int e = blockIdx.x * blockDim.x + threadIdx.x;
    if (e < E) atomicAdd(&cnt[ei[E + e]], 1);
}

__global__ void scan1_k(const int* __restrict__ in, int* __restrict__ out,
                        int* __restrict__ bsum, int n) {
    __shared__ int lds[256];
    int t = threadIdx.x;
    int i = blockIdx.x * 256 + t;
    int v = (i < n) ? in[i] : 0;
    lds[t] = v;
    __syncthreads();
#pragma unroll
    for (int o = 1; o < 256; o <<= 1) {
        int u = (t >= o) ? lds[t - o] : 0;
        __syncthreads();
        lds[t] += u;
        __syncthreads();
    }
    if (i < n) out[i] = lds[t] - v;
    if (t == 255) bsum[blockIdx.x] = lds[255];
}

__global__ void scan2_k(const int* __restrict__ bsum, int* __restrict__ boff, int nb) {
    __shared__ int lds[256];
    int t = threadIdx.x;
    int v = (t < nb) ? bsum[t] : 0;
    lds[t] = v;
    __syncthreads();
#pragma unroll
    for (int o = 1; o < 256; o <<= 1) {
        int u = (t >= o) ? lds[t - o] : 0;
        __syncthreads();
        lds[t] += u;
        __syncthreads();
    }
    if (t < nb) boff[t] = lds[t] - v;
}

__global__ void scan3_k(int* __restrict__ rs, const int* __restrict__ boff, int n, int E) {
    int i = blockIdx.x * 256 + threadIdx.x;
    if (i < n) rs[i] += boff[blockIdx.x];
    if (i == 0) rs[n] = E;
}

__global__ void scatter_k(const int* __restrict__ ei, int* __restrict__ cursor,
                          int2* __restrict__ es, int E) {
    int e = blockIdx.x * blockDim.x + threadIdx.x;
    if (e < E) {
        int dst = ei[E + e];
        int slot = atomicAdd(&cursor[dst], 1);
        es[slot] = make_int2(ei[e], e);
    }
}

// ---------------- edge-LN precompute ----------------
// Per layer l: wm[k]=mean_c W[c][k]; bm=mean(b); Wp=W-wm; bp=b-bm.
// Wg[k][c] = Wp[c][k]*g[c]; bg[c] = bp[c]*g[c]
// M[k][j]  = sum_c Wp[c][k]*Wp[c][j];  v[k]=2*sum_c Wp[c][k]*bp[c];  s0=sum bp^2
// => 128*var(attr a) = a^T M a + v.a + s0 (no 128-wide reduce per edge).
__global__ void prep_k(const float* __restrict__ edge_W, const float* __restrict__ edge_b,
                       const float* __restrict__ edge_g, float* __restrict__ Wg3,
                       float* __restrict__ bg3, float* __restrict__ M3,
                       float* __restrict__ v3, float* __restrict__ s03)
{
    const int l = blockIdx.x;
    const float* W = edge_W + (size_t)l * HD * EDGED;
    const float* b = edge_b + l * HD;
    const float* g = edge_g + l * HD;
    __shared__ float Wp[HD * EDGED];
    __shared__ float bp[HD];
    __shared__ float wm[EDGED];
    __shared__ float bmS;
    const int t = threadIdx.x;
#pragma unroll
    for (int m = 0; m < 8; ++m) Wp[m * 256 + t] = W[m * 256 + t];
    __syncthreads();
    if (t < EDGED) {
        float s = 0.f;
        for (int c = 0; c < HD; ++c) s += Wp[c * EDGED + t];
        wm[t] = s * (1.f / HD);
    } else if (t == EDGED) {
        float s = 0.f;
        for (int c = 0; c < HD; ++c) s += b[c];
        bmS = s * (1.f / HD);
    }
    __syncthreads();
    if (t < HD) bp[t] = b[t] - bmS;
    __syncthreads();
#pragma unroll
    for (int m = 0; m < 8; ++m) {
        int idx = m * 256 + t;
        int c = idx >> 4, k = idx & 15;
        float val = Wp[idx] - wm[k];
        Wp[idx] = val;
        Wg3[(size_t)l * 2048 + k * HD + c] = val * g[c];
    }
    if (t < HD) bg3[l * HD + t] = bp[t] * g[t];
    __syncthreads();
    {
        int k = t >> 4, j = t & 15;
        float s = 0.f;
        for (int c = 0; c < HD; ++c) s += Wp[c * EDGED + k] * Wp[c * EDGED + j];
        M3[l * 256 + t] = s;
    }
    if (t < EDGED) {
        float s = 0.f;
        for (int c = 0; c < HD; ++c) s += Wp[c * EDGED + t] * bp[c];
        v3[l * EDGED + t] = 2.f * s;
    } else if (t == EDGED) {
        float s = 0.f;
        for (int c = 0; c < HD; ++c) s += bp[c] * bp[c];
        s03[l] = s;
    }
}

// Per CSR slot: gather attr row once, emit rsqrt(var+eps) for all 3 layers
__launch_bounds__(256)
__global__ void einv_k(const int2* __restrict__ es, const float* __restrict__ eattr,
                       const float* __restrict__ M3, const float* __restrict__ v3,
                       const float* __restrict__ s03, float* __restrict__ einv, int E)
{
    __shared__ float Ms[3 * 256];
    __shared__ float vs[3 * 16];
    __shared__ float s0s[4];
    const int t = threadIdx.x;
    for (int i = t; i < 768; i += 256) Ms[i] = M3[i];
    if (t < 48) vs[t] = v3[t];
    if (t < 3) s0s[t] = s03[t];
    __syncthreads();
    int slot = blockIdx.x * 256 + t;
    if (slot >= E) return;
    int eid = es[slot].y;
    const float4* ap = (const float4*)(eattr + (size_t)eid * EDGED);
    float4 A0 = ap[0], A1 = ap[1], A2 = ap[2], A3 = ap[3];
    float a[16] = {A0.x, A0.y, A0.z, A0.w, A1.x, A1.y, A1.z, A1.w,
                   A2.x, A2.y, A2.z, A2.w, A3.x, A3.y, A3.z, A3.w};
#pragma unroll
    for (int l = 0; l < 3; ++l) {
        float q = s0s[l];
#pragma unroll
        for (int k = 0; k < 16; ++k) {
            const float* Mr = &Ms[l * 256 + k * 16];
            float tk = vs[l * 16 + k];
#pragma unroll
            for (int j = 0; j < 16; ++j) tk = fmaf(Mr[j], a[j], tk);
            q = fmaf(a[k], tk, q);
        }
        einv[(size_t)l * E + slot] = rsqrtf(q * (1.f / HD) + LN_EPS);
    }
}

// ---------------- MFMA GEMM, split-bf16 (bf16x3 ~ fp32 accuracy) ------------
// C[M,NC] = act(A[M,K] @ W^T + bias), W given as bf16 hi/lo in [NC][K] layout.
// Each wave: 32 rows (2 x 16-row MFMA groups) x all NC cols. Block = 4 waves
// = 128 rows. A-frag: 8 contiguous fp32 per lane -> hi/lo bf16 in-register.
// B-frag: W[n=lane&15 (+16*nt)][k=quad*8 .. +7] -> contiguous 16B loads (L2-hot).
// acc = hi*hi + hi*lo + lo*hi (lo*lo ~ 2^-18 rel, dropped).
template<int K, int NC, int ACT, int STATS>
__launch_bounds__(256)
__global__ void mgemm_k(const float* __restrict__ A, const __bf16* __restrict__ Whi,
                        const __bf16* __restrict__ Wlo, const float* __restrict__ bias,
                        float* __restrict__ C, int M, float* __restrict__ stats)
{
    constexpr int NT = NC / 16;
    __shared__ float st_lds[2][256];

    const int t    = threadIdx.x;
    const int lane = t & 63;
    const int wv   = t >> 6;
    const int ln15 = lane & 15;
    const int quad = lane >> 4;
    const int row_base = blockIdx.x * 128 + wv * 32;

    f32x4 acc[2][NT];
#pragma unroll
    for (int g = 0; g < 2; ++g)
#pragma unroll
        for (int nt = 0; nt < NT; ++nt)
#pragma unroll
            for (int r = 0; r < 4; ++r) acc[g][nt][r] = 0.f;

    for (int kc = 0; kc < K; kc += 32) {
        bf16x8 ahi[2], alo[2];
#pragma unroll
        for (int g = 0; g < 2; ++g) {
            int row = row_base + g * 16 + ln15;
            float4 a0 = make_float4(0.f, 0.f, 0.f, 0.f), a1 = a0;
            if (row < M) {
                const float* p = A + (size_t)row * K + kc + quad * 8;
                a0 = *(const float4*)p;
                a1 = *(const float4*)(p + 4);
            }
            float av[8] = {a0.x, a0.y, a0.z, a0.w, a1.x, a1.y, a1.z, a1.w};
#pragma unroll
            for (int j = 0; j < 8; ++j) {
                __bf16 hh = (__bf16)av[j];
                ahi[g][j] = hh;
                alo[g][j] = (__bf16)(av[j] - (float)hh);
            }
        }
#pragma unroll
        for (int nt = 0; nt < NT; ++nt) {
            const size_t boff = (size_t)(nt * 16 + ln15) * K + kc + quad * 8;
            bf16x8 bh = *(const bf16x8*)(Whi + boff);
            bf16x8 bl = *(const bf16x8*)(Wlo + boff);
#pragma unroll
            for (int g = 0; g < 2; ++g) {
                acc[g][nt] = __builtin_amdgcn_mfma_f32_16x16x32_bf16(ahi[g], bh, acc[g][nt], 0, 0, 0);
                acc[g][nt] = __builtin_amdgcn_mfma_f32_16x16x32_bf16(ahi[g], bl, acc[g][nt], 0, 0, 0);
                acc[g][nt] = __builtin_amdgcn_mfma_f32_16x16x32_bf16(alo[g], bh, acc[g][nt], 0, 0, 0);
            }
        }
    }

    if (STATS) {
        if (t < NC) { st_lds[0][t] = 0.f; st_lds[1][t] = 0.f; }
        __syncthreads();
    }

    float bv[NT];
#pragma unroll
    for (int nt = 0; nt < NT; ++nt) bv[nt] = bias[nt * 16 + ln15];

    float s1[NT], s2[NT];
#pragma unroll
    for (int nt = 0; nt < NT; ++nt) { s1[nt] = 0.f; s2[nt] = 0.f; }

#pragma unroll
    for (int g = 0; g < 2; ++g)
#pragma unroll
        for (int r = 0; r < 4; ++r) {
            int row = row_base + g * 16 + quad * 4 + r;
            if (row < M) {
#pragma unroll
                for (int nt = 0; nt < NT; ++nt) {
                    float v = acc[g][nt][r] + bv[nt];
                    if (ACT == 1) v = gelu_exact(v);
                    C[(size_t)row * NC + nt * 16 + ln15] = v;
                    if (STATS) { s1[nt] += v; s2[nt] += v * v; }
                }
            }
        }

    if (STATS) {
#pragma unroll
        for (int nt = 0; nt < NT; ++nt) {
            atomicAdd(&st_lds[0][nt * 16 + ln15], s1[nt]);
            atomicAdd(&st_lds[1][nt * 16 + ln15], s2[nt]);
        }
        __syncthreads();
        if (t < NC) {
            atomicAdd(&stats[t],      st_lds[0][t]);
            atomicAdd(&stats[HD + t], st_lds[1][t]);
        }
    }
}

// LayerNorm(+ReLU) over rows of 128, one wave per node
__global__ void ln_relu_k(const float* __restrict__ y, const float* __restrict__ gam,
                          const float* __restrict__ bet, float* __restrict__ h, int N)
{
    int lane = threadIdx.x & 63;
    int c0 = lane * 2;
    float2 g2 = *(const float2*)&gam[c0];
    float2 b2 = *(const float2*)&bet[c0];
    int wid = (blockIdx.x * blockDim.x + threadIdx.x) >> 6;
    int nw  = (gridDim.x * blockDim.x) >> 6;
    for (int n = wid; n < N; n += nw) {
        float2 v = *(const float2*)&y[(size_t)n * HD + c0];
        float s = v.x + v.y;
        float q = v.x * v.x + v.y * v.y;
#pragma unroll
        for (int o = 32; o > 0; o >>= 1) { s += __shfl_xor(s, o, 64); q += __shfl_xor(q, o, 64); }
        float mu  = s * (1.f / 128.f);
        float inv = rsqrtf(q * (1.f / 128.f) - mu * mu + LN_EPS);
        float2 r;
        r.x = fmaxf(fmaf((v.x - mu) * inv, g2.x, b2.x), 0.f);
        r.y = fmaxf(fmaf((v.y - mu) * inv, g2.y, b2.y), 0.f);
        *(float2*)&h[(size_t)n * HD + c0] = r;
    }
}

// one wave: embed the single learned self-loop attr -> sl_vec[128]
__global__ void sl_embed_k(const float* __restrict__ attr, const float* __restrict__ W,
                           const float* __restrict__ bias, const float* __restrict__ gam,
                           const float* __restrict__ bet, float* __restrict__ out)
{
    int lane = threadIdx.x;
    int c0 = lane * 2, c1 = c0 + 1;
    float acc0 = bias[c0], acc1 = bias[c1];
    for (int k = 0; k < EDGED; ++k) {
        float a = attr[k];
        acc0 = fmaf(a, W[c0 * EDGED + k], acc0);
        acc1 = fmaf(a, W[c1 * EDGED + k], acc1);
    }
    float s = acc0 + acc1, q = acc0 * acc0 + acc1 * acc1;
#pragma unroll
    for (int o = 32; o > 0; o >>= 1) { s += __shfl_xor(s, o, 64); q += __shfl_xor(q, o, 64); }
    float mu  = s * (1.f / 128.f);
    float inv = rsqrtf(q * (1.f / 128.f) - mu * mu + LN_EPS);
    out[c0] = fmaxf(fmaf((acc0 - mu) * inv, gam[c0], bet[c0]), 0.f);
    out[c1] = fmaxf(fmaf((acc1 - mu) * inv, gam[c1], bet[c1]), 0.f);
}

// ---------------- pull aggregation v3: reg weights, no per-edge reductions ----
// lane owns channels {lane, lane+64}; edge-embed weights in VGPRs; attr chunk
// staged in per-wave LDS; LN var via precomputed einv.
// NOTE: all __shfl must execute at FULL wave exec (bpermute from an inactive
// lane is undefined) — shfls are hoisted out of predicated code.
__launch_bounds__(256)
__global__ void pull3_k(const float* __restrict__ h, const int2* __restrict__ es,
                        const int* __restrict__ rs, const float* __restrict__ eattr,
                        const float* __restrict__ einv, const float* __restrict__ slv,
                        const float* __restrict__ Wg, const float* __restrict__ bg,
                        const float* __restrict__ bet, float* __restrict__ aggr, int N)
{
    __shared__ float alds_all[4][64 * EDGED];   // 16 KB: per-wave attr staging
    const int t = threadIdx.x;
    const int lane = t & 63;
    const int wv = t >> 6;
    float* alds = alds_all[wv];

    const int c1 = lane, c2 = lane + 64;
    float w1[16], w2[16];
#pragma unroll
    for (int k = 0; k < 16; ++k) {
        w1[k] = Wg[k * HD + c1];
        w2[k] = Wg[k * HD + c2];
    }
    const float bg1 = bg[c1], bg2 = bg[c2];
    const float bt1 = bet[c1], bt2 = bet[c2];

    const int n = (blockIdx.x << 2) + wv;
    if (n >= N) return;

    float acc1 = h[(size_t)n * HD + c1] + slv[c1];
    float acc2 = h[(size_t)n * HD + c2] + slv[c2];

    const int beg = rs[n], end = rs[n + 1];
    for (int s0 = beg; s0 < end; s0 += 64) {
        int m = end - s0; if (m > 64) m = 64;
        int2 se = make_int2(0, 0);
        float iv = 0.f;
        if (lane < m) { se = es[s0 + lane]; iv = einv[s0 + lane]; }
        // stage attrs: fixed 4 iterations; shfl at full exec (jsrc always a
        // valid lane id 0..63); memory ops predicated on idx < 4m.
#pragma unroll
        for (int it = 0; it < 4; ++it) {
            int idx  = (it << 6) + lane;
            int jsrc = idx >> 2;                       // 0..63
            int eid  = __shfl(se.y, jsrc, 64);         // full-exec shfl
            if (idx < (m << 2)) {
                float4 av = *(const float4*)&eattr[(size_t)eid * EDGED + ((idx & 3) << 2)];
                *(float4*)&alds[idx << 2] = av;
            }
        }
        asm volatile("s_waitcnt lgkmcnt(0)" ::: "memory");
        for (int j = 0; j < m; ++j) {
            float4 A0 = *(const float4*)&alds[j * EDGED];
            float4 A1 = *(const float4*)&alds[j * EDGED + 4];
            float4 A2 = *(const float4*)&alds[j * EDGED + 8];
            float4 A3 = *(const float4*)&alds[j * EDGED + 12];
            int   src = __shfl(se.x, j, 64);
            float ivj = __shfl(iv,   j, 64);
            float hv1 = h[(size_t)src * HD + c1];
            float hv2 = h[(size_t)src * HD + c2];
            float a[16] = {A0.x, A0.y, A0.z, A0.w, A1.x, A1.y, A1.z, A1.w,
                           A2.x, A2.y, A2.z, A2.w, A3.x, A3.y, A3.z, A3.w};
            float p1 = bg1, q1 = 0.f, p2 = bg2, q2 = 0.f;
#pragma unroll
            for (int k = 0; k < 16; k += 2) {
                p1 = fmaf(a[k],     w1[k],     p1);
                q1 = fmaf(a[k + 1], w1[k + 1], q1);
                p2 = fmaf(a[k],     w2[k],     p2);
                q2 = fmaf(a[k + 1], w2[k + 1], q2);
            }
            float v1 = fmaxf(fmaf(p1 + q1, ivj, bt1), 0.f);
            float v2 = fmaxf(fmaf(p2 + q2, ivj, bt2), 0.f);
            acc1 += v1 + hv1;
            acc2 += v2 + hv2;
        }
    }
    aggr[(size_t)n * HD + c1] = acc1;
    aggr[(size_t)n * HD + c2] = acc2;
}

// BatchNorm apply from accumulated column sums; optional ReLU
__global__ void bn_k(const float* __restrict__ hl, const float* __restrict__ stats,
                     const float* __restrict__ gam, const float* __restrict__ bet,
                     float* __restrict__ out, int total4, float invN, int relu)
{
    int idx = blockIdx.x * blockDim.x + threadIdx.x;
    if (idx < total4) {
        int c4 = idx & 31;
        float4 x  = ((const float4*)hl)[idx];
        float4 s1 = ((const float4*)stats)[c4];
        float4 s2 = ((const float4*)stats)[32 + c4];
        float4 g  = ((const float4*)gam)[c4];
        float4 b  = ((const float4*)bet)[c4];
        float4 r;
        {
            float m = s1.x * invN; float v = s2.x * invN - m * m;
            r.x = fmaf((x.x - m) * rsqrtf(v + LN_EPS), g.x, b.x);
        }
        {
            float m = s1.y * invN; float v = s2.y * invN - m * m;
            r.y = fmaf((x.y - m) * rsqrtf(v + LN_EPS), g.y, b.y);
        }
        {
            float m = s1.z * invN; float v = s2.z * invN - m * m;
            r.z = fmaf((x.z - m) * rsqrtf(v + LN_EPS), g.z, b.z);
        }
        {
            float m = s1.w * invN; float v = s2.w * invN - m * m;
            r.w = fmaf((x.w - m) * rsqrtf(v + LN_EPS), g.w, b.w);
        }
        if (relu) {
            r.x = fmaxf(r.x, 0.f); r.y = fmaxf(r.y, 0.f);
            r.z = fmaxf(r.z, 0.f); r.w = fmaxf(r.w, 0.f);
        }
        ((float4*)out)[idx] = r;
    }
}

extern "C" void kernel_launch(void* const* d_in, const int* in_sizes, int n_in,
                              void* d_out, int out_size, void* d_ws, size_t ws_size,
                              hipStream_t stream)
{
    const float* x       = (const float*)d_in[0];
    const int*   ei      = (const int*)d_in[1];
    const float* eattr   = (const float*)d_in[2];
    const float* node_W  = (const float*)d_in[3];
    const float* node_b  = (const float*)d_in[4];
    const float* node_g  = (const float*)d_in[5];
    const float* node_be = (const float*)d_in[6];
    const float* edge_W  = (const float*)d_in[7];
    const float* edge_b  = (const float*)d_in[8];
    const float* edge_g  = (const float*)d_in[9];
    const float* edge_be = (const float*)d_in[10];
    const float* sl_attr = (const float*)d_in[11];
    const float* W1      = (const float*)d_in[12];
    const float* b1      = (const float*)d_in[13];
    const float* W2      = (const float*)d_in[14];
    const float* b2      = (const float*)d_in[15];
    const float* bn_g    = (const float*)d_in[16];
    const float* bn_b    = (const float*)d_in[17];

    const int N = in_sizes[0] / NODED;
    const int E = in_sizes[1] / 2;

    float* ws    = (float*)d_ws;
    float* h     = ws;                         // N*128
    float* aggr  = h    + (size_t)N * HD;      // N*128
    float* z     = aggr + (size_t)N * HD;      // N*256
    float* slv   = z    + (size_t)N * 256;     // 128
    float* stats = slv  + 128;                 // 256
    int*   cnt    = (int*)(stats + 256);         // N
    int*   cursor = cnt + N;                     // N
    int*   bsum   = cursor + N;                  // 256
    int*   boff   = bsum + 256;                  // 256
    int*   rs     = boff + 256;                  // N+2
    int2*  es     = (int2*)(rs + N + 2);         // E (8B aligned)
    float* einv   = (float*)(es + E);            // 3*E
    float* Wg3    = einv + (size_t)3 * E;        // 3*2048
    float* bg3    = Wg3 + 3 * 2048;              // 3*128
    float* M3     = bg3 + 3 * 128;               // 3*256
    float* v3     = M3 + 3 * 256;                // 3*16
    float* s03    = v3 + 3 * 16;                 // 3 (+1 pad)
    __bf16* nWhi  = (__bf16*)(s03 + 4);          // 128*64
    __bf16* nWlo  = nWhi + HD * NODED;
    __bf16* W1hi  = nWlo + HD * NODED;           // 3*256*128
    __bf16* W1lo  = W1hi + 3 * 256 * HD;
    __bf16* W2hi  = W1lo + 3 * 256 * HD;         // 3*128*256
    __bf16* W2lo  = W2hi + 3 * HD * 256;

    // weight split-bf16 conversion (layouts already [N][K] row-major)
    wconv_k<<<(HD * NODED + 255) / 256, 256, 0, stream>>>(node_W, nWhi, nWlo, HD * NODED);
    wconv_k<<<(3 * 256 * HD + 255) / 256, 256, 0, stream>>>(W1, W1hi, W1lo, 3 * 256 * HD);
    wconv_k<<<(3 * 256 * HD + 255) / 256, 256, 0, stream>>>(W2, W2hi, W2lo, 3 * 256 * HD);

    // edge-LN precompute (all 3 layers)
    prep_k<<<3, 256, 0, stream>>>(edge_W, edge_b, edge_g, Wg3, bg3, M3, v3, s03);

    // ---- CSR build ----
    const int eblocks = (E + 255) / 256;
    const int nblocks = (N + 255) / 256;
    hipMemsetAsync(cnt, 0, (size_t)N * sizeof(int), stream);
    hist_k<<<eblocks, 256, 0, stream>>>(ei, cnt, E);
    scan1_k<<<nblocks, 256, 0, stream>>>(cnt, rs, bsum, N);
    scan2_k<<<1, 256, 0, stream>>>(bsum, boff, nblocks);
    scan3_k<<<nblocks, 256, 0, stream>>>(rs, boff, N, E);
    hipMemcpyAsync(cursor, rs, (size_t)N * sizeof(int), hipMemcpyDeviceToDevice, stream);
    scatter_k<<<eblocks, 256, 0, stream>>>(ei, cursor, es, E);

    // per-slot inv-std for all 3 layers (one attr gather)
    einv_k<<<eblocks, 256, 0, stream>>>(es, eattr, M3, v3, s03, einv, E);

    const int mb      = (N + 127) / 128;
    const int total4  = N * (HD / 4);
    const int vblocks = (total4 + 255) / 256;
    const int pblocks = (N + 3) / 4;

    // node embed: Linear (MFMA) -> LN -> ReLU
    mgemm_k<NODED, HD, 0, 0><<<mb, 256, 0, stream>>>(x, nWhi, nWlo, node_b, z, N, nullptr);
    ln_relu_k<<<pblocks, 256, 0, stream>>>(z, node_g, node_be, h, N);

    for (int l = 0; l < 3; ++l) {
        const float* eW  = edge_W  + (size_t)l * HD * EDGED;
        const float* eb  = edge_b  + l * HD;
        const float* eg  = edge_g  + l * HD;
        const float* ebe = edge_be + l * HD;

        sl_embed_k<<<1, 64, 0, stream>>>(sl_attr + l * EDGED, eW, eb, eg, ebe, slv);
        pull3_k<<<pblocks, 256, 0, stream>>>(h, es, rs, eattr, einv + (size_t)l * E, slv,
                                             Wg3 + (size_t)l * 2048, bg3 + l * HD,
                                             ebe, aggr, N);

        mgemm_k<HD, 256, 1, 0><<<mb, 256, 0, stream>>>(
            aggr, W1hi + (size_t)l * 256 * HD, W1lo + (size_t)l * 256 * HD,
            b1 + l * 256, z, N, nullptr);

        hipMemsetAsync(stats, 0, 256 * sizeof(float), stream);
        mgemm_k<256, HD, 0, 1><<<mb, 256, 0, stream>>>(
            z, W2hi + (size_t)l * HD * 256, W2lo + (size_t)l * HD * 256,
            b2 + l * HD, (float*)d_out, N, stats);

        bn_k<<<vblocks, 256, 0, stream>>>((const float*)d_out, stats, bn_g + l * HD, bn_b + l * HD,
                                          (l < 2) ? h : (float*)d_out, total4, 1.f / N, (l < 2) ? 1 : 0);
    }
}